// Round 1
// baseline (926.547 us; speedup 1.0000x reference)
//
#include <hip/hip_runtime.h>
#include <hip/hip_bf16.h>
#include <stdint.h>

#define N_VOX 300000
#define KNB   27
#define COUT  96
#define EPS   1e-5f
#define BM    256
#define NBLK  ((N_VOX + BM - 1) / BM)   // 1172

typedef __attribute__((ext_vector_type(8))) short  short8;
typedef __attribute__((ext_vector_type(4))) float  f32x4;
typedef __attribute__((ext_vector_type(4))) float  float4v;
typedef __attribute__((ext_vector_type(4))) unsigned short ushort4v;

__device__ __forceinline__ unsigned short f2bf(float f) {
    uint32_t u = __float_as_uint(f);
    uint32_t r = (u + 0x7FFFu + ((u >> 16) & 1u)) >> 16;
    return (unsigned short)r;
}
__device__ __forceinline__ float bf2f(unsigned short b) {
    return __uint_as_float(((uint32_t)b) << 16);
}

// ---------------- cast x: f32 -> bf16, vectorized ----------------
__global__ void cast_x_kernel(const float4v* __restrict__ x, ushort4v* __restrict__ xb, int n4) {
    int i = blockIdx.x * blockDim.x + threadIdx.x;
    int stride = gridDim.x * blockDim.x;
    for (; i < n4; i += stride) {
        float4v v = x[i];
        ushort4v o;
        o.x = f2bf(v.x); o.y = f2bf(v.y); o.z = f2bf(v.z); o.w = f2bf(v.w);
        xb[i] = o;
    }
}

// ------------- cast + transpose W: [K][Cin][Cout] f32 -> [K][Cout][Cin] bf16 -------------
__global__ void cast_w_kernel(const float* __restrict__ W, unsigned short* __restrict__ Wt,
                              int Cin, int total) {
    int idx = blockIdx.x * blockDim.x + threadIdx.x;
    if (idx >= total) return;
    int per_k = Cin * COUT;
    int k = idx / per_k;
    int r = idx - k * per_k;
    int c = r / Cin;          // cout
    int ci = r - c * Cin;     // cin
    Wt[idx] = f2bf(W[(k * Cin + ci) * COUT + c]);
}

// ---------------- sparse conv: out[i] = sum_k X[nbr[i,k]] @ W[k] ----------------
// A-frag loaded per-lane directly from global (gather); B-frags from Wt (global, L2-hot),
// held in registers across the wave's 4 row-fragments. No LDS in the K-loop.
template <int CIN, bool F32OUT>
__launch_bounds__(256, 2)
__global__ void conv_kernel(const unsigned short* __restrict__ X,
                            const int* __restrict__ nbrs,
                            const unsigned short* __restrict__ Wt,
                            void* __restrict__ out,
                            float* __restrict__ partials) {
    __shared__ int   nbr_s[BM * KNB];       // 27648 B
    __shared__ float stat_s[4][2 * COUT];   // 3072 B

    const int tid  = threadIdx.x;
    const int blk  = blockIdx.x;
    const int base = blk * BM;

    for (int i = tid; i < BM * KNB; i += 256) {
        int gi = base * KNB + i;
        nbr_s[i] = (gi < N_VOX * KNB) ? nbrs[gi] : 0;
    }
    __syncthreads();

    const int w  = tid >> 6;
    const int l  = tid & 63;
    const int lo = l & 15;
    const int hi = l >> 4;
    constexpr int S = CIN / 32;

    f32x4 acc[4][6];
#pragma unroll
    for (int f = 0; f < 4; ++f)
#pragma unroll
        for (int cf = 0; cf < 6; ++cf)
            acc[f][cf] = (f32x4){0.f, 0.f, 0.f, 0.f};

#pragma unroll 1
    for (int k = 0; k < KNB; ++k) {
        // B fragments: Wt[k][cout=cf*16+lo][cin=s*32+hi*8 .. +8]
        short8 b[S][6];
        const unsigned short* wk = Wt + (k * COUT + lo) * CIN + hi * 8;
#pragma unroll
        for (int cf = 0; cf < 6; ++cf)
#pragma unroll
            for (int s = 0; s < S; ++s)
                b[s][cf] = *(const short8*)(wk + cf * 16 * CIN + s * 32);

#pragma unroll
        for (int f = 0; f < 4; ++f) {
            int v   = w * 64 + f * 16 + lo;
            int row = nbr_s[v * KNB + k];
            const unsigned short* xp = X + row * CIN + hi * 8;
#pragma unroll
            for (int s = 0; s < S; ++s) {
                short8 a = *(const short8*)(xp + s * 32);
#pragma unroll
                for (int cf = 0; cf < 6; ++cf)
                    acc[f][cf] = __builtin_amdgcn_mfma_f32_16x16x32_bf16(a, b[s][cf], acc[f][cf], 0, 0, 0);
            }
        }
    }

    // epilogue: store + per-block BN stats
    float s_sum[6], s_sq[6];
#pragma unroll
    for (int cf = 0; cf < 6; ++cf) { s_sum[cf] = 0.f; s_sq[cf] = 0.f; }

#pragma unroll
    for (int f = 0; f < 4; ++f) {
        int m0 = base + w * 64 + f * 16 + hi * 4;
#pragma unroll
        for (int i = 0; i < 4; ++i) {
            int m = m0 + i;
            bool valid = (m < N_VOX);
#pragma unroll
            for (int cf = 0; cf < 6; ++cf) {
                float val = acc[f][cf][i];
                int col = cf * 16 + lo;
                if (valid) {
                    if (F32OUT) ((float*)out)[m * COUT + col] = val;
                    else ((unsigned short*)out)[m * COUT + col] = f2bf(val);
                    s_sum[cf] += val;
                    s_sq[cf]  += val * val;
                }
            }
        }
    }

#pragma unroll
    for (int cf = 0; cf < 6; ++cf) {
        float s = s_sum[cf], q = s_sq[cf];
        s += __shfl_xor(s, 16); q += __shfl_xor(q, 16);
        s += __shfl_xor(s, 32); q += __shfl_xor(q, 32);
        if (hi == 0) {
            stat_s[w][cf * 16 + lo]        = s;
            stat_s[w][COUT + cf * 16 + lo] = q;
        }
    }
    __syncthreads();
    if (tid < 2 * COUT) {
        float v = stat_s[0][tid] + stat_s[1][tid] + stat_s[2][tid] + stat_s[3][tid];
        partials[blk * (2 * COUT) + tid] = v;
    }
}

// ---------------- finalize: partials -> fused scale/bias ----------------
__global__ void finalize_kernel(const float* __restrict__ partials, int nblk,
                                const float* __restrict__ gamma, const float* __restrict__ beta,
                                float* __restrict__ scale, float* __restrict__ bias) {
    int c = blockIdx.x;        // 0..95
    int tid = threadIdx.x;     // 256
    float s = 0.f, q = 0.f;
    for (int b = tid; b < nblk; b += 256) {
        s += partials[b * 192 + c];
        q += partials[b * 192 + 96 + c];
    }
    __shared__ float rs[4], rq[4];
#pragma unroll
    for (int m = 1; m <= 32; m <<= 1) { s += __shfl_xor(s, m); q += __shfl_xor(q, m); }
    int wid = tid >> 6, lane = tid & 63;
    if (lane == 0) { rs[wid] = s; rq[wid] = q; }
    __syncthreads();
    if (tid == 0) {
        s = rs[0] + rs[1] + rs[2] + rs[3];
        q = rq[0] + rq[1] + rq[2] + rq[3];
        float mu  = s / (float)N_VOX;
        float var = q / (float)N_VOX - mu * mu;
        float rsg = rsqrtf(var + EPS);
        float sc  = gamma[c] * rsg;
        scale[c] = sc;
        bias[c]  = beta[c] - mu * sc;
    }
}

// ---------------- BN-affine + ReLU, in-place (bf16) ----------------
__global__ void bnrelu_bf16_kernel(unsigned short* __restrict__ h,
                                   const float* __restrict__ scale,
                                   const float* __restrict__ bias, int total) {
    __shared__ float sc[COUT], bi[COUT];
    if (threadIdx.x < COUT) { sc[threadIdx.x] = scale[threadIdx.x]; bi[threadIdx.x] = bias[threadIdx.x]; }
    __syncthreads();
    int i = blockIdx.x * blockDim.x + threadIdx.x;
    int stride = gridDim.x * blockDim.x;
    for (; i < total; i += stride) {
        int c = i % COUT;
        float v = bf2f(h[i]) * sc[c] + bi[c];
        h[i] = f2bf(fmaxf(v, 0.f));
    }
}

// ---------------- BN-affine + ReLU, in-place (f32) ----------------
__global__ void bnrelu_f32_kernel(float* __restrict__ h,
                                  const float* __restrict__ scale,
                                  const float* __restrict__ bias, int total) {
    __shared__ float sc[COUT], bi[COUT];
    if (threadIdx.x < COUT) { sc[threadIdx.x] = scale[threadIdx.x]; bi[threadIdx.x] = bias[threadIdx.x]; }
    __syncthreads();
    int i = blockIdx.x * blockDim.x + threadIdx.x;
    int stride = gridDim.x * blockDim.x;
    for (; i < total; i += stride) {
        int c = i % COUT;
        float v = h[i] * sc[c] + bi[c];
        h[i] = fmaxf(v, 0.f);
    }
}

extern "C" void kernel_launch(void* const* d_in, const int* in_sizes, int n_in,
                              void* d_out, int out_size, void* d_ws, size_t ws_size,
                              hipStream_t stream) {
    const float* x    = (const float*)d_in[0];
    const int*   nbrs = (const int*)  d_in[1];
    const float* W1   = (const float*)d_in[2];
    const float* g1   = (const float*)d_in[3];
    const float* b1   = (const float*)d_in[4];
    const float* W2   = (const float*)d_in[5];
    const float* g2   = (const float*)d_in[6];
    const float* b2   = (const float*)d_in[7];

    char* ws = (char*)d_ws;
    // byte offsets (all 256-aligned)
    unsigned short* xb  = (unsigned short*)(ws);                       // 38,400,000 B
    unsigned short* h0  = (unsigned short*)(ws + 38400000);            // 57,600,000 B
    unsigned short* w1t = (unsigned short*)(ws + 96000000);            //    331,776 B
    unsigned short* w2t = (unsigned short*)(ws + 96331776);            //    497,664 B
    float* p1    = (float*)(ws + 96829440);                            //    900,096 B
    float* p2    = (float*)(ws + 97729536);                            //    900,096 B
    float* sb    = (float*)(ws + 98629632);                            // scale1,bias1,scale2,bias2
    float* scale1 = sb;
    float* bias1  = sb + 96;
    float* scale2 = sb + 192;
    float* bias2  = sb + 288;

    // 1) casts
    cast_x_kernel<<<2048, 256, 0, stream>>>((const float4v*)x, (ushort4v*)xb, N_VOX * 64 / 4);
    {
        int tot1 = KNB * 64 * COUT;
        cast_w_kernel<<<(tot1 + 255) / 256, 256, 0, stream>>>(W1, w1t, 64, tot1);
        int tot2 = KNB * 96 * COUT;
        cast_w_kernel<<<(tot2 + 255) / 256, 256, 0, stream>>>(W2, w2t, 96, tot2);
    }

    // 2) conv1 (Cin=64) -> h0 bf16 (+ stats partials)
    conv_kernel<64, false><<<NBLK, 256, 0, stream>>>(xb, nbrs, w1t, h0, p1);

    // 3) BN1 finalize + affine/relu in place on h0
    finalize_kernel<<<96, 256, 0, stream>>>(p1, NBLK, g1, b1, scale1, bias1);
    bnrelu_bf16_kernel<<<2048, 256, 0, stream>>>(h0, scale1, bias1, N_VOX * COUT);

    // 4) conv2 (Cin=96) -> d_out f32 raw (+ stats partials)
    conv_kernel<96, true><<<NBLK, 256, 0, stream>>>(h0, nbrs, w2t, d_out, p2);

    // 5) BN2 finalize + affine/relu in place on d_out
    finalize_kernel<<<96, 256, 0, stream>>>(p2, NBLK, g2, b2, scale2, bias2);
    bnrelu_f32_kernel<<<2048, 256, 0, stream>>>((float*)d_out, scale2, bias2, N_VOX * COUT);
}

// Round 2
// 586.233 us; speedup vs baseline: 1.5805x; 1.5805x over previous
//
#include <hip/hip_runtime.h>
#include <hip/hip_bf16.h>
#include <stdint.h>

#define N_VOX 300000
#define KNB   27
#define COUT  96
#define EPS   1e-5f
#define BM    256
#define NBLK  ((N_VOX + BM - 1) / BM)   // 1172

typedef __attribute__((ext_vector_type(8))) short  short8;
typedef __attribute__((ext_vector_type(4))) float  f32x4;
typedef __attribute__((ext_vector_type(4))) float  float4v;
typedef __attribute__((ext_vector_type(4))) unsigned short ushort4v;

__device__ __forceinline__ unsigned short f2bf(float f) {
    uint32_t u = __float_as_uint(f);
    uint32_t r = (u + 0x7FFFu + ((u >> 16) & 1u)) >> 16;
    return (unsigned short)r;
}
__device__ __forceinline__ float bf2f(unsigned short b) {
    return __uint_as_float(((uint32_t)b) << 16);
}

// ---------------- cast x: f32 -> bf16, vectorized ----------------
__global__ void cast_x_kernel(const float4v* __restrict__ x, ushort4v* __restrict__ xb, int n4) {
    int i = blockIdx.x * blockDim.x + threadIdx.x;
    int stride = gridDim.x * blockDim.x;
    for (; i < n4; i += stride) {
        float4v v = x[i];
        ushort4v o;
        o.x = f2bf(v.x); o.y = f2bf(v.y); o.z = f2bf(v.z); o.w = f2bf(v.w);
        xb[i] = o;
    }
}

// ------------- cast + relayout W: [K][Cin][Cout] f32 -> staging-unit order bf16 -------------
// Unit order (16B units): u = ((k*6*S + cf*S + s)*64 + hi*16 + lo),
// unit holds W[k][cin = s*32 + hi*8 + j][cout = cf*16 + lo], j = 0..7.
// This makes per-k LDS staging a plain contiguous copy AND ds_read_b128 at
// (base + lane*16) conflict-free.
template <int S>
__global__ void cast_w_kernel(const float* __restrict__ W, unsigned short* __restrict__ Wt,
                              int total) {
    int idx = blockIdx.x * blockDim.x + threadIdx.x;
    if (idx >= total) return;
    int j    = idx & 7;
    int ual  = idx >> 3;
    int lane = ual & 63;
    int lo   = lane & 15;
    int hi   = lane >> 4;
    int rest = ual >> 6;            // k*6*S + cf*S + s
    int s    = rest % S;
    int cfk  = rest / S;
    int cf   = cfk % 6;
    int k    = cfk / 6;
    int cin  = s * 32 + hi * 8 + j;
    int cout = cf * 16 + lo;
    Wt[idx] = f2bf(W[(k * (S * 32) + cin) * COUT + cout]);
}

// ---------------- sparse conv: out[i] = sum_k X[nbr[i,k]] @ W[k] ----------------
// 8 waves x (32 rows x 96 cout), acc[2][6] (48 AGPR). B staged in LDS (double-
// buffered, reg-staged T14-style), A gathered per-lane straight into MFMA frags,
// double-buffered one k-step ahead to hide L3 random-gather latency.
template <int CIN, bool F32OUT>
__launch_bounds__(512, 4)
__global__ void conv_kernel(const unsigned short* __restrict__ X,
                            const int* __restrict__ nbrs,
                            const unsigned short* __restrict__ Wt,
                            void* __restrict__ out,
                            float* __restrict__ partials) {
    constexpr int S      = CIN / 32;
    constexpr int BUNITS = 6 * S * 64;          // 16B units per k (768 / 1152)
    constexpr int CHUNKS = BUNITS / 64;         // 1KB wave-chunks per k (12 / 18)
    constexpr int NSTG   = (CHUNKS + 7) / 8;    // staging regs per wave (2 / 3)

    __shared__ int nbr_s[BM * KNB];                               // 27648 B
    __shared__ __align__(16) unsigned short bbuf[2][BUNITS * 8];  // 2x12KB / 2x18KB

    const int tid  = threadIdx.x;
    const int blk  = blockIdx.x;
    const int base = blk * BM;
    const int w    = tid >> 6;   // 0..7
    const int l    = tid & 63;
    const int lo   = l & 15;
    const int hi   = l >> 4;

    // stage neighbor indices (coalesced)
    for (int i = tid; i < BM * KNB; i += 512) {
        int gi = base * KNB + i;
        nbr_s[i] = (gi < N_VOX * KNB) ? nbrs[gi] : 0;
    }

    f32x4 acc[2][6];
#pragma unroll
    for (int f = 0; f < 2; ++f)
#pragma unroll
        for (int cf = 0; cf < 6; ++cf)
            acc[f][cf] = (f32x4){0.f, 0.f, 0.f, 0.f};

    short8 a0[2][S], a1[2][S], stg[NSTG];

    auto stage_load = [&](int k) {
        const unsigned short* src = Wt + (size_t)k * (BUNITS * 8);
#pragma unroll
        for (int n = 0; n < NSTG; ++n) {
            int c = w + n * 8;
            if (c < CHUNKS)
                stg[n] = *(const short8*)(src + c * 512 + l * 8);
        }
    };
    auto stage_write = [&](unsigned short* buf) {
#pragma unroll
        for (int n = 0; n < NSTG; ++n) {
            int c = w + n * 8;
            if (c < CHUNKS)
                *(short8*)&buf[c * 512 + l * 8] = stg[n];
        }
    };
    auto loadA = [&](int k, short8 (&a)[2][S]) {
#pragma unroll
        for (int f = 0; f < 2; ++f) {
            int v   = w * 32 + f * 16 + lo;
            int row = nbr_s[v * KNB + k];
            const unsigned short* xp = X + (size_t)row * CIN + hi * 8;
#pragma unroll
            for (int s = 0; s < S; ++s)
                a[f][s] = *(const short8*)(xp + s * 32);
        }
    };
    auto mfmaP = [&](const unsigned short* buf, short8 (&a)[2][S]) {
#pragma unroll
        for (int cf = 0; cf < 6; ++cf)
#pragma unroll
            for (int s = 0; s < S; ++s) {
                short8 b = *(const short8*)&buf[((cf * S + s) * 64 + l) * 8];
                acc[0][cf] = __builtin_amdgcn_mfma_f32_16x16x32_bf16(a[0][s], b, acc[0][cf], 0, 0, 0);
                acc[1][cf] = __builtin_amdgcn_mfma_f32_16x16x32_bf16(a[1][s], b, acc[1][cf], 0, 0, 0);
            }
    };

    // prologue: B(0) -> bbuf[0], A(0) -> a0
    stage_load(0);
    __syncthreads();            // nbr_s visible
    stage_write(bbuf[0]);
    loadA(0, a0);
    __syncthreads();            // bbuf[0] visible to all waves

    // main loop: two k-steps per iteration, fixed even/odd buffer parity
#pragma unroll 1
    for (int kk = 0; kk < KNB - 1; kk += 2) {
        // step even: compute k=kk from (bbuf0, a0); prefetch kk+1 -> (bbuf1, a1)
        stage_load(kk + 1);
        loadA(kk + 1, a1);
        mfmaP(bbuf[0], a0);
        stage_write(bbuf[1]);
        __syncthreads();
        // step odd: compute k=kk+1 from (bbuf1, a1); prefetch kk+2 -> (bbuf0, a0)
        stage_load(kk + 2);
        loadA(kk + 2, a0);
        mfmaP(bbuf[1], a1);
        stage_write(bbuf[0]);
        __syncthreads();
    }
    // tail: k = 26 (even parity)
    mfmaP(bbuf[0], a0);
    __syncthreads();            // before stats overlay reuses bbuf space

    // epilogue: store + per-block BN stats
    float s_sum[6], s_sq[6];
#pragma unroll
    for (int cf = 0; cf < 6; ++cf) { s_sum[cf] = 0.f; s_sq[cf] = 0.f; }

#pragma unroll
    for (int f = 0; f < 2; ++f) {
        int m0 = base + w * 32 + f * 16 + hi * 4;
#pragma unroll
        for (int i = 0; i < 4; ++i) {
            int m = m0 + i;
            bool valid = (m < N_VOX);
#pragma unroll
            for (int cf = 0; cf < 6; ++cf) {
                float val = acc[f][cf][i];
                int col = cf * 16 + lo;
                if (valid) {
                    if (F32OUT) ((float*)out)[(size_t)m * COUT + col] = val;
                    else ((unsigned short*)out)[(size_t)m * COUT + col] = f2bf(val);
                    s_sum[cf] += val;
                    s_sq[cf]  += val * val;
                }
            }
        }
    }

    float* stat = (float*)bbuf;   // 8*192 floats = 6144 B, overlays dead B buffer
#pragma unroll
    for (int cf = 0; cf < 6; ++cf) {
        float s = s_sum[cf], q = s_sq[cf];
        s += __shfl_xor(s, 16); q += __shfl_xor(q, 16);
        s += __shfl_xor(s, 32); q += __shfl_xor(q, 32);
        if (hi == 0) {
            stat[w * 192 + cf * 16 + lo]       = s;
            stat[w * 192 + COUT + cf * 16 + lo] = q;
        }
    }
    __syncthreads();
    if (tid < 2 * COUT) {
        float v = 0.f;
#pragma unroll
        for (int ww = 0; ww < 8; ++ww) v += stat[ww * 192 + tid];
        partials[blk * (2 * COUT) + tid] = v;
    }
}

// ---------------- finalize: partials -> fused scale/bias ----------------
__global__ void finalize_kernel(const float* __restrict__ partials, int nblk,
                                const float* __restrict__ gamma, const float* __restrict__ beta,
                                float* __restrict__ scale, float* __restrict__ bias) {
    int c = blockIdx.x;        // 0..95
    int tid = threadIdx.x;     // 256
    float s = 0.f, q = 0.f;
    for (int b = tid; b < nblk; b += 256) {
        s += partials[b * 192 + c];
        q += partials[b * 192 + 96 + c];
    }
    __shared__ float rs[4], rq[4];
#pragma unroll
    for (int m = 1; m <= 32; m <<= 1) { s += __shfl_xor(s, m); q += __shfl_xor(q, m); }
    int wid = tid >> 6, lane = tid & 63;
    if (lane == 0) { rs[wid] = s; rq[wid] = q; }
    __syncthreads();
    if (tid == 0) {
        s = rs[0] + rs[1] + rs[2] + rs[3];
        q = rq[0] + rq[1] + rq[2] + rq[3];
        float mu  = s / (float)N_VOX;
        float var = q / (float)N_VOX - mu * mu;
        float rsg = rsqrtf(var + EPS);
        float sc  = gamma[c] * rsg;
        scale[c] = sc;
        bias[c]  = beta[c] - mu * sc;
    }
}

// ---------------- BN-affine + ReLU, in-place (bf16) ----------------
__global__ void bnrelu_bf16_kernel(unsigned short* __restrict__ h,
                                   const float* __restrict__ scale,
                                   const float* __restrict__ bias, int total) {
    __shared__ float sc[COUT], bi[COUT];
    if (threadIdx.x < COUT) { sc[threadIdx.x] = scale[threadIdx.x]; bi[threadIdx.x] = bias[threadIdx.x]; }
    __syncthreads();
    int i = blockIdx.x * blockDim.x + threadIdx.x;
    int stride = gridDim.x * blockDim.x;
    for (; i < total; i += stride) {
        int c = i % COUT;
        float v = bf2f(h[i]) * sc[c] + bi[c];
        h[i] = f2bf(fmaxf(v, 0.f));
    }
}

// ---------------- BN-affine + ReLU, in-place (f32) ----------------
__global__ void bnrelu_f32_kernel(float* __restrict__ h,
                                  const float* __restrict__ scale,
                                  const float* __restrict__ bias, int total) {
    __shared__ float sc[COUT], bi[COUT];
    if (threadIdx.x < COUT) { sc[threadIdx.x] = scale[threadIdx.x]; bi[threadIdx.x] = bias[threadIdx.x]; }
    __syncthreads();
    int i = blockIdx.x * blockDim.x + threadIdx.x;
    int stride = gridDim.x * blockDim.x;
    for (; i < total; i += stride) {
        int c = i % COUT;
        float v = h[i] * sc[c] + bi[c];
        h[i] = fmaxf(v, 0.f);
    }
}

extern "C" void kernel_launch(void* const* d_in, const int* in_sizes, int n_in,
                              void* d_out, int out_size, void* d_ws, size_t ws_size,
                              hipStream_t stream) {
    const float* x    = (const float*)d_in[0];
    const int*   nbrs = (const int*)  d_in[1];
    const float* W1   = (const float*)d_in[2];
    const float* g1   = (const float*)d_in[3];
    const float* b1   = (const float*)d_in[4];
    const float* W2   = (const float*)d_in[5];
    const float* g2   = (const float*)d_in[6];
    const float* b2   = (const float*)d_in[7];

    char* ws = (char*)d_ws;
    unsigned short* xb  = (unsigned short*)(ws);                       // 38,400,000 B
    unsigned short* h0  = (unsigned short*)(ws + 38400000);            // 57,600,000 B
    unsigned short* w1t = (unsigned short*)(ws + 96000000);            //    331,776 B
    unsigned short* w2t = (unsigned short*)(ws + 96331776);            //    497,664 B
    float* p1    = (float*)(ws + 96829440);                            //    900,096 B
    float* p2    = (float*)(ws + 97729536);                            //    900,096 B
    float* sb    = (float*)(ws + 98629632);
    float* scale1 = sb;
    float* bias1  = sb + 96;
    float* scale2 = sb + 192;
    float* bias2  = sb + 288;

    // 1) casts
    cast_x_kernel<<<2048, 256, 0, stream>>>((const float4v*)x, (ushort4v*)xb, N_VOX * 64 / 4);
    {
        int tot1 = KNB * 64 * COUT;
        cast_w_kernel<2><<<(tot1 + 255) / 256, 256, 0, stream>>>(W1, w1t, tot1);
        int tot2 = KNB * 96 * COUT;
        cast_w_kernel<3><<<(tot2 + 255) / 256, 256, 0, stream>>>(W2, w2t, tot2);
    }

    // 2) conv1 (Cin=64) -> h0 bf16 (+ stats partials)
    conv_kernel<64, false><<<NBLK, 512, 0, stream>>>(xb, nbrs, w1t, h0, p1);

    // 3) BN1 finalize + affine/relu in place on h0
    finalize_kernel<<<96, 256, 0, stream>>>(p1, NBLK, g1, b1, scale1, bias1);
    bnrelu_bf16_kernel<<<2048, 256, 0, stream>>>(h0, scale1, bias1, N_VOX * COUT);

    // 4) conv2 (Cin=96) -> d_out f32 raw (+ stats partials)
    conv_kernel<96, true><<<NBLK, 512, 0, stream>>>(h0, nbrs, w2t, d_out, p2);

    // 5) BN2 finalize + affine/relu in place on d_out
    finalize_kernel<<<96, 256, 0, stream>>>(p2, NBLK, g2, b2, scale2, bias2);
    bnrelu_f32_kernel<<<2048, 256, 0, stream>>>((float*)d_out, scale2, bias2, N_VOX * COUT);
}